// Round 3
// baseline (3021.548 us; speedup 1.0000x reference)
//
#include <hip/hip_runtime.h>
#include <cmath>

#define NNODES 100000
#define NEDGES 1600000
#define INC 512
#define HC 256
#define NLAYERS 8

typedef _Float16 half4v __attribute__((ext_vector_type(4)));
typedef float floatx4 __attribute__((ext_vector_type(4)));

struct __attribute__((aligned(8))) EdgeP { int s; float w; };

// ---- edge dtype detection: int64 little-endian with values < 2^31 => odd 32-bit words all zero.
__global__ void k_detect(const unsigned int* __restrict__ eb, int* __restrict__ mode) {
  int lane = threadIdx.x;  // 64 threads
  unsigned v = eb[2 * lane + 1];
  unsigned long long nz = __ballot(v != 0u);
  if (lane == 0) *mode = (nz == 0ull) ? 1 : 0;
}

__device__ __forceinline__ int edge_at(const void* eb, int m, int i) {
  return m ? (int)((const long long*)eb)[i] : ((const int*)eb)[i];
}

// ---------------- CSR build ----------------

__global__ __launch_bounds__(256) void k_zero2(int* __restrict__ a, int* __restrict__ b, int n) {
  int i = blockIdx.x * 256 + threadIdx.x;
  if (i < n) { a[i] = 0; b[i] = 0; }
}

__global__ __launch_bounds__(256) void k_count(const void* __restrict__ eb, const int* __restrict__ mode,
                                               int* __restrict__ counts) {
  int e = blockIdx.x * 256 + threadIdx.x;
  if (e >= NEDGES) return;
  int m = *mode;
  atomicAdd(&counts[edge_at(eb, m, NEDGES + e)], 1);
}

__global__ __launch_bounds__(256) void k_dinv(const int* __restrict__ counts, float* __restrict__ dinv) {
  int i = blockIdx.x * 256 + threadIdx.x;
  if (i < NNODES) dinv[i] = 1.0f / sqrtf((float)counts[i] + 1.0f);  // +1 self loop
}

__global__ __launch_bounds__(256) void k_scan1(const int* __restrict__ counts, int* __restrict__ rowptr,
                                               int* __restrict__ partials) {
  __shared__ int sm[256];
  int i = blockIdx.x * 256 + threadIdx.x;
  int v = (i < NNODES) ? counts[i] : 0;
  sm[threadIdx.x] = v;
  __syncthreads();
  for (int off = 1; off < 256; off <<= 1) {
    int u = (threadIdx.x >= off) ? sm[threadIdx.x - off] : 0;
    __syncthreads();
    sm[threadIdx.x] += u;
    __syncthreads();
  }
  if (i < NNODES) rowptr[i] = sm[threadIdx.x] - v;
  if (threadIdx.x == 255) partials[blockIdx.x] = sm[255];
}

__global__ __launch_bounds__(512) void k_scan2(int* __restrict__ partials, int* __restrict__ rowptr, int nb) {
  __shared__ int sm[512];
  int t = threadIdx.x;
  int v = (t < nb) ? partials[t] : 0;
  sm[t] = v;
  __syncthreads();
  for (int off = 1; off < 512; off <<= 1) {
    int u = (t >= off) ? sm[t - off] : 0;
    __syncthreads();
    sm[t] += u;
    __syncthreads();
  }
  if (t < nb) partials[t] = sm[t] - v;
  if (t == 0) rowptr[NNODES] = NEDGES;
}

__global__ __launch_bounds__(256) void k_scan3(int* __restrict__ rowptr, const int* __restrict__ partials) {
  int i = blockIdx.x * 256 + threadIdx.x;
  if (i < NNODES) rowptr[i] += partials[blockIdx.x];
}

__global__ __launch_bounds__(256) void k_fill(const void* __restrict__ eb, const int* __restrict__ mode,
                                              const int* __restrict__ rowptr,
                                              int* __restrict__ cursor, const float* __restrict__ dinv,
                                              EdgeP* __restrict__ ep) {
  int e = blockIdx.x * 256 + threadIdx.x;
  if (e >= NEDGES) return;
  int m = *mode;
  int r = edge_at(eb, m, e), c = edge_at(eb, m, NEDGES + e);
  int p = rowptr[c] + atomicAdd(&cursor[c], 1);
  EdgeP pr; pr.s = r; pr.w = dinv[r] * dinv[c];
  ep[p] = pr;
}

// ---------------- dense: out = act( ob*mfid + beta*(A @ W) + bias ) ----------------
// All-f32 VALU GEMM. Block: 64 rows x 256 cols. Thread (tr,tc): rows r0..r0+3,
// cols {tc*4 + 64g + e}. W slab [64][256] f32 in LDS (64 KB). ds_read pattern:
// word offset k*256 + tc*4 + 64g -> bank 4*tc%32 -> 2-way (free, m136).
// In-place safe when outf == mfid == A (last layer): all reads pre-barrier,
// rows are block-exclusive.

__global__ __launch_bounds__(256) void k_dense(const float* A, int lda, int K,
                                               const float* W,      // [K][256] row-major (d_in)
                                               const float* bias,   // or null
                                               const float* mfid,   // identity term f32, or null
                                               float ob, float beta, int relu,
                                               _Float16* outh, _Float16* outh2, float* outf) {
  __shared__ float Wl[64][256];
  int t = threadIdx.x;
  int tr = t >> 4, tc = t & 15;
  int r0 = blockIdx.x * 64 + tr * 4;
  int cr[4];
#pragma unroll
  for (int i = 0; i < 4; ++i) { int r = r0 + i; cr[i] = (r < NNODES) ? r : (NNODES - 1); }

  floatx4 acc[4][4] = {};
  for (int s = 0; s < K; s += 64) {
    {
      const floatx4* src = (const floatx4*)(W + (size_t)s * HC);
      floatx4* dst = (floatx4*)&Wl[0][0];
#pragma unroll
      for (int i = 0; i < 16; ++i) dst[t + i * 256] = src[t + i * 256];
    }
    __syncthreads();
    for (int kk = 0; kk < 64; kk += 4) {
      floatx4 a[4];
#pragma unroll
      for (int i = 0; i < 4; ++i)
        a[i] = *(const floatx4*)(A + (size_t)cr[i] * lda + s + kk);
#pragma unroll
      for (int j = 0; j < 4; ++j) {
        floatx4 w0 = *(const floatx4*)&Wl[kk + j][tc * 4];
        floatx4 w1 = *(const floatx4*)&Wl[kk + j][tc * 4 + 64];
        floatx4 w2 = *(const floatx4*)&Wl[kk + j][tc * 4 + 128];
        floatx4 w3 = *(const floatx4*)&Wl[kk + j][tc * 4 + 192];
#pragma unroll
        for (int i = 0; i < 4; ++i) {
          float aj = a[i][j];
          acc[i][0] += w0 * aj;
          acc[i][1] += w1 * aj;
          acc[i][2] += w2 * aj;
          acc[i][3] += w3 * aj;
        }
      }
    }
    __syncthreads();
  }

  // fold identity / bias / relu (all reads pre-barrier)
#pragma unroll
  for (int i = 0; i < 4; ++i)
#pragma unroll
    for (int g = 0; g < 4; ++g) {
      floatx4 v = acc[i][g];
      if (mfid) {
        floatx4 idv = *(const floatx4*)(mfid + (size_t)cr[i] * HC + tc * 4 + g * 64);
        v = ob * idv + beta * v;
      }
      if (bias) {
        floatx4 bv = *(const floatx4*)(bias + tc * 4 + g * 64);
        v = v + bv;
      }
      if (relu) {
        v[0] = fmaxf(v[0], 0.0f); v[1] = fmaxf(v[1], 0.0f);
        v[2] = fmaxf(v[2], 0.0f); v[3] = fmaxf(v[3], 0.0f);
      }
      acc[i][g] = v;
    }
  __syncthreads();   // in-place safety (outf may alias mfid/A)
#pragma unroll
  for (int i = 0; i < 4; ++i) {
    if (r0 + i >= NNODES) continue;
#pragma unroll
    for (int g = 0; g < 4; ++g) {
      size_t off = (size_t)(r0 + i) * HC + tc * 4 + g * 64;
      floatx4 v = acc[i][g];
      if (outf) *(floatx4*)(outf + off) = v;
      if (outh) {
        half4v hv = { (_Float16)v[0], (_Float16)v[1], (_Float16)v[2], (_Float16)v[3] };
        *(half4v*)(outh + off) = hv;
      }
      if (outh2) {
        half4v hv = { (_Float16)v[0], (_Float16)v[1], (_Float16)v[2], (_Float16)v[3] };
        *(half4v*)(outh2 + off) = hv;
      }
    }
  }
}

// ---------------- SpMM + residual: mf = 0.9*(D^-1/2 A_hat D^-1/2 h) + 0.1*h0 ----------------

__global__ __launch_bounds__(256) void k_spmm(const _Float16* __restrict__ h, const _Float16* __restrict__ h0,
                                              const int* __restrict__ rowptr, const EdgeP* __restrict__ ep,
                                              const float* __restrict__ dinv, float* __restrict__ mf) {
  int wave = threadIdx.x >> 6, lane = threadIdx.x & 63;
  int node = blockIdx.x * 4 + wave;
  if (node >= NNODES) return;
  int c = lane * 4;
  size_t base = (size_t)node * HC + c;
  float di = dinv[node];
  float ws = di * di;
  half4v hv = *(const half4v*)(h + base);
  float a0 = ws * (float)hv[0], a1 = ws * (float)hv[1], a2 = ws * (float)hv[2], a3 = ws * (float)hv[3];
  int t = rowptr[node], en = rowptr[node + 1];
  for (; t + 1 < en; t += 2) {
    EdgeP p0 = ep[t], p1 = ep[t + 1];
    half4v x0 = *(const half4v*)(h + (size_t)p0.s * HC + c);
    half4v x1 = *(const half4v*)(h + (size_t)p1.s * HC + c);
    a0 += p0.w * (float)x0[0] + p1.w * (float)x1[0];
    a1 += p0.w * (float)x0[1] + p1.w * (float)x1[1];
    a2 += p0.w * (float)x0[2] + p1.w * (float)x1[2];
    a3 += p0.w * (float)x0[3] + p1.w * (float)x1[3];
  }
  if (t < en) {
    EdgeP p0 = ep[t];
    half4v x0 = *(const half4v*)(h + (size_t)p0.s * HC + c);
    a0 += p0.w * (float)x0[0];
    a1 += p0.w * (float)x0[1];
    a2 += p0.w * (float)x0[2];
    a3 += p0.w * (float)x0[3];
  }
  half4v h0v = *(const half4v*)(h0 + base);
  float4 m = make_float4(0.9f * a0 + 0.1f * (float)h0v[0],
                         0.9f * a1 + 0.1f * (float)h0v[1],
                         0.9f * a2 + 0.1f * (float)h0v[2],
                         0.9f * a3 + 0.1f * (float)h0v[3]);
  *(float4*)(mf + base) = m;
}

// ---------------- host ----------------

extern "C" void kernel_launch(void* const* d_in, const int* in_sizes, int n_in,
                              void* d_out, int out_size, void* d_ws, size_t ws_size,
                              hipStream_t stream) {
  const float* x = (const float*)d_in[0];
  const void* ei = d_in[1];                    // int32 or int64 — detected on device
  const float* wemb = (const float*)d_in[2];   // [512][256]
  const float* bemb = (const float*)d_in[3];
  const float* wc = (const float*)d_in[4];     // [8][256][256]
  (void)in_sizes; (void)n_in; (void)out_size; (void)ws_size;

  char* ws = (char*)d_ws;
  size_t o = 0;
  auto alloc = [&](size_t bytes) -> char* {
    char* p = ws + o;
    o = (o + bytes + 511) & ~(size_t)511;
    return p;
  };
  // total workspace ~116.8 MB
  _Float16* hh      = (_Float16*)alloc((size_t)NNODES * HC * 2);  // 51.2 MB
  _Float16* h0h     = (_Float16*)alloc((size_t)NNODES * HC * 2);  // 51.2 MB
  EdgeP*    ep      = (EdgeP*)alloc((size_t)NEDGES * 8);          // 12.8 MB
  int*      counts  = (int*)alloc((size_t)NNODES * 4);
  int*      cursor  = (int*)alloc((size_t)NNODES * 4);
  int*      rowptr  = (int*)alloc((size_t)(NNODES + 1) * 4);
  float*    dinv    = (float*)alloc((size_t)NNODES * 4);
  int*      partials= (int*)alloc(2048);
  int*      mode    = (int*)alloc(256);
  float*    mf      = (float*)d_out;           // f32 message/identity buffer lives in d_out

  const int NB = (NNODES + 255) / 256;  // 391
  const int GEMM_GRID = (NNODES + 63) / 64;  // 1563

  k_detect<<<1, 64, 0, stream>>>((const unsigned int*)ei, mode);
  k_zero2<<<NB, 256, 0, stream>>>(counts, cursor, NNODES);
  k_count<<<(NEDGES + 255) / 256, 256, 0, stream>>>(ei, mode, counts);
  k_dinv<<<NB, 256, 0, stream>>>(counts, dinv);
  k_scan1<<<NB, 256, 0, stream>>>(counts, rowptr, partials);
  k_scan2<<<1, 512, 0, stream>>>(partials, rowptr, NB);
  k_scan3<<<NB, 256, 0, stream>>>(rowptr, partials);
  k_fill<<<(NEDGES + 255) / 256, 256, 0, stream>>>(ei, mode, rowptr, cursor, dinv, ep);

  // h0 = relu(x @ Wemb + b); stored f16 into hh and h0h
  k_dense<<<GEMM_GRID, 256, 0, stream>>>(x, INC, INC, wemb, bemb,
                                         (const float*)nullptr, 0.0f, 1.0f, 1,
                                         hh, h0h, (float*)nullptr);

  for (int l = 0; l < NLAYERS; ++l) {
    float beta = (float)log(0.5 / (double)(l + 1) + 1.0);
    float ob = 1.0f - beta;
    k_spmm<<<NNODES / 4, 256, 0, stream>>>(hh, h0h, rowptr, ep, dinv, mf);
    bool last = (l == NLAYERS - 1);
    // out = ob*mf + beta*(mf @ W); relu except last; last writes f32 into d_out (in-place on mf)
    k_dense<<<GEMM_GRID, 256, 0, stream>>>(mf, HC, HC, wc + (size_t)l * HC * HC,
                                           (const float*)nullptr, mf, ob, beta, last ? 0 : 1,
                                           last ? (_Float16*)nullptr : hh,
                                           (_Float16*)nullptr,
                                           last ? (float*)d_out : (float*)nullptr);
  }
}

// Round 4
// 2646.425 us; speedup vs baseline: 1.1417x; 1.1417x over previous
//
#include <hip/hip_runtime.h>
#include <cmath>

#define NNODES 100000
#define NEDGES 1600000
#define INC 512
#define HC 256
#define NLAYERS 8

typedef _Float16 half8 __attribute__((ext_vector_type(8)));
typedef _Float16 half4v __attribute__((ext_vector_type(4)));
typedef float floatx4 __attribute__((ext_vector_type(4)));

struct __attribute__((aligned(8))) EdgeP { int s; float w; };

// ---- edge dtype detection: int64 little-endian with values < 2^31 => odd 32-bit words all zero.
__global__ void k_detect(const unsigned int* __restrict__ eb, int* __restrict__ mode) {
  int lane = threadIdx.x;  // 64 threads
  unsigned v = eb[2 * lane + 1];
  unsigned long long nz = __ballot(v != 0u);
  if (lane == 0) *mode = (nz == 0ull) ? 1 : 0;
}

__device__ __forceinline__ int edge_at(const void* eb, int m, int i) {
  return m ? (int)((const long long*)eb)[i] : ((const int*)eb)[i];
}

// ---------------- CSR build (unchanged from green R3) ----------------

__global__ __launch_bounds__(256) void k_zero2(int* __restrict__ a, int* __restrict__ b, int n) {
  int i = blockIdx.x * 256 + threadIdx.x;
  if (i < n) { a[i] = 0; b[i] = 0; }
}

__global__ __launch_bounds__(256) void k_count(const void* __restrict__ eb, const int* __restrict__ mode,
                                               int* __restrict__ counts) {
  int e = blockIdx.x * 256 + threadIdx.x;
  if (e >= NEDGES) return;
  int m = *mode;
  atomicAdd(&counts[edge_at(eb, m, NEDGES + e)], 1);
}

__global__ __launch_bounds__(256) void k_dinv(const int* __restrict__ counts, float* __restrict__ dinv) {
  int i = blockIdx.x * 256 + threadIdx.x;
  if (i < NNODES) dinv[i] = 1.0f / sqrtf((float)counts[i] + 1.0f);  // +1 self loop
}

__global__ __launch_bounds__(256) void k_scan1(const int* __restrict__ counts, int* __restrict__ rowptr,
                                               int* __restrict__ partials) {
  __shared__ int sm[256];
  int i = blockIdx.x * 256 + threadIdx.x;
  int v = (i < NNODES) ? counts[i] : 0;
  sm[threadIdx.x] = v;
  __syncthreads();
  for (int off = 1; off < 256; off <<= 1) {
    int u = (threadIdx.x >= off) ? sm[threadIdx.x - off] : 0;
    __syncthreads();
    sm[threadIdx.x] += u;
    __syncthreads();
  }
  if (i < NNODES) rowptr[i] = sm[threadIdx.x] - v;
  if (threadIdx.x == 255) partials[blockIdx.x] = sm[255];
}

__global__ __launch_bounds__(512) void k_scan2(int* __restrict__ partials, int* __restrict__ rowptr, int nb) {
  __shared__ int sm[512];
  int t = threadIdx.x;
  int v = (t < nb) ? partials[t] : 0;
  sm[t] = v;
  __syncthreads();
  for (int off = 1; off < 512; off <<= 1) {
    int u = (t >= off) ? sm[t - off] : 0;
    __syncthreads();
    sm[t] += u;
    __syncthreads();
  }
  if (t < nb) partials[t] = sm[t] - v;
  if (t == 0) rowptr[NNODES] = NEDGES;
}

__global__ __launch_bounds__(256) void k_scan3(int* __restrict__ rowptr, const int* __restrict__ partials) {
  int i = blockIdx.x * 256 + threadIdx.x;
  if (i < NNODES) rowptr[i] += partials[blockIdx.x];
}

__global__ __launch_bounds__(256) void k_fill(const void* __restrict__ eb, const int* __restrict__ mode,
                                              const int* __restrict__ rowptr,
                                              int* __restrict__ cursor, const float* __restrict__ dinv,
                                              EdgeP* __restrict__ ep) {
  int e = blockIdx.x * 256 + threadIdx.x;
  if (e >= NEDGES) return;
  int m = *mode;
  int r = edge_at(eb, m, e), c = edge_at(eb, m, NEDGES + e);
  int p = rowptr[c] + atomicAdd(&cursor[c], 1);
  EdgeP pr; pr.s = r; pr.w = dinv[r] * dinv[c];
  ep[p] = pr;
}

// ---------------- weight transposes to f16 ----------------
// W_embed [512][256] -> WT [256][512]
__global__ __launch_bounds__(256) void k_tr_wemb(const float* __restrict__ W, _Float16* __restrict__ WT) {
  int idx = blockIdx.x * 256 + threadIdx.x;        // 131072 = c*512 + k
  int k = idx & 511, c = idx >> 9;
  WT[idx] = (_Float16)W[k * 256 + c];
}
// W_convs [8][256][256] (l,k,n) -> WT [8][256][256] (l,n,k)
__global__ __launch_bounds__(256) void k_tr_wc(const float* __restrict__ W, _Float16* __restrict__ WT) {
  int idx = blockIdx.x * 256 + threadIdx.x;        // 524288 = l*65536 + n*256 + k
  int k = idx & 255, n = (idx >> 8) & 255, l = idx >> 16;
  WT[idx] = (_Float16)W[(l * 256 + k) * 256 + n];
}

// ---------------- MFMA dense: out = act( ob*mfid + beta*(A @ WT^T) + bias ) ----------------
// Block: 64 rows x 256 cols, 4 waves; wave w owns cols w*64..w*64+63 (4x4 16x16 frags).
// A read f32, converted in-reg. B = WT[col][k] f16, read direct (L1/L2-resident).
// No LDS. D frag map: row=(lane>>4)*4+q, col=lane&15 (m89-verified).
// In-place safe for outf==mfid==A (last layer): A reads are block-local rows,
// __syncthreads separates all A reads from epilogue writes; mfid[off] is
// read/written by exactly one thread.

__global__ __launch_bounds__(256) void k_dense(const float* A, int lda, int K,
                                               const _Float16* __restrict__ WT,
                                               const float* __restrict__ bias,
                                               const float* mfid,
                                               float ob, float beta, int relu,
                                               _Float16* __restrict__ outh, _Float16* __restrict__ outh2,
                                               float* outf) {
  int wave = threadIdx.x >> 6, lane = threadIdx.x & 63;
  int r = lane & 15, g = lane >> 4;
  int row0 = blockIdx.x * 64;
  int c0 = wave * 64;
  int ar[4];
#pragma unroll
  for (int rt = 0; rt < 4; ++rt) {
    int rr = row0 + rt * 16 + r;
    ar[rt] = (rr < NNODES) ? rr : (NNODES - 1);
  }
  floatx4 acc[4][4] = {};
  for (int ks = 0; ks < K; ks += 32) {
    half8 a[4], b[4];
#pragma unroll
    for (int rt = 0; rt < 4; ++rt) {
      const float* ap = A + (size_t)ar[rt] * lda + ks + g * 8;
      float4 p0 = *(const float4*)ap;
      float4 p1 = *(const float4*)(ap + 4);
      a[rt] = half8{ (_Float16)p0.x, (_Float16)p0.y, (_Float16)p0.z, (_Float16)p0.w,
                     (_Float16)p1.x, (_Float16)p1.y, (_Float16)p1.z, (_Float16)p1.w };
    }
#pragma unroll
    for (int ct = 0; ct < 4; ++ct)
      b[ct] = *(const half8*)(WT + (size_t)(c0 + ct * 16 + r) * K + ks + g * 8);
#pragma unroll
    for (int rt = 0; rt < 4; ++rt)
#pragma unroll
      for (int ct = 0; ct < 4; ++ct)
        acc[rt][ct] = __builtin_amdgcn_mfma_f32_16x16x32_f16(a[rt], b[ct], acc[rt][ct], 0, 0, 0);
  }
  __syncthreads();   // in-place safety: all A reads complete before any store below
#pragma unroll
  for (int rt = 0; rt < 4; ++rt) {
#pragma unroll
    for (int q = 0; q < 4; ++q) {
      int row = row0 + rt * 16 + g * 4 + q;
      if (row >= NNODES) continue;
#pragma unroll
      for (int ct = 0; ct < 4; ++ct) {
        int col = c0 + ct * 16 + r;
        size_t off = (size_t)row * HC + col;
        float v = acc[rt][ct][q];
        if (mfid) v = ob * mfid[off] + beta * v;
        if (bias) v += bias[col];
        if (relu) v = fmaxf(v, 0.0f);
        if (outf) outf[off] = v;
        if (outh) outh[off] = (_Float16)v;
        if (outh2) outh2[off] = (_Float16)v;
      }
    }
  }
}

// ---------------- SpMM + residual: mf = 0.9*(D^-1/2 A_hat D^-1/2 h) + 0.1*h0 ----------------

__global__ __launch_bounds__(256) void k_spmm(const _Float16* __restrict__ h, const _Float16* __restrict__ h0,
                                              const int* __restrict__ rowptr, const EdgeP* __restrict__ ep,
                                              const float* __restrict__ dinv, float* __restrict__ mf) {
  int wave = threadIdx.x >> 6, lane = threadIdx.x & 63;
  int node = blockIdx.x * 4 + wave;
  if (node >= NNODES) return;
  int c = lane * 4;
  size_t base = (size_t)node * HC + c;
  float di = dinv[node];
  float ws = di * di;
  half4v hv = *(const half4v*)(h + base);
  float a0 = ws * (float)hv[0], a1 = ws * (float)hv[1], a2 = ws * (float)hv[2], a3 = ws * (float)hv[3];
  int t = rowptr[node], en = rowptr[node + 1];
  for (; t + 1 < en; t += 2) {
    EdgeP p0 = ep[t], p1 = ep[t + 1];
    half4v x0 = *(const half4v*)(h + (size_t)p0.s * HC + c);
    half4v x1 = *(const half4v*)(h + (size_t)p1.s * HC + c);
    a0 += p0.w * (float)x0[0] + p1.w * (float)x1[0];
    a1 += p0.w * (float)x0[1] + p1.w * (float)x1[1];
    a2 += p0.w * (float)x0[2] + p1.w * (float)x1[2];
    a3 += p0.w * (float)x0[3] + p1.w * (float)x1[3];
  }
  if (t < en) {
    EdgeP p0 = ep[t];
    half4v x0 = *(const half4v*)(h + (size_t)p0.s * HC + c);
    a0 += p0.w * (float)x0[0];
    a1 += p0.w * (float)x0[1];
    a2 += p0.w * (float)x0[2];
    a3 += p0.w * (float)x0[3];
  }
  half4v h0v = *(const half4v*)(h0 + base);
  float4 m = make_float4(0.9f * a0 + 0.1f * (float)h0v[0],
                         0.9f * a1 + 0.1f * (float)h0v[1],
                         0.9f * a2 + 0.1f * (float)h0v[2],
                         0.9f * a3 + 0.1f * (float)h0v[3]);
  *(float4*)(mf + base) = m;
}

// ---------------- host ----------------

extern "C" void kernel_launch(void* const* d_in, const int* in_sizes, int n_in,
                              void* d_out, int out_size, void* d_ws, size_t ws_size,
                              hipStream_t stream) {
  const float* x = (const float*)d_in[0];
  const void* ei = d_in[1];                    // int32 or int64 — detected on device
  const float* wemb = (const float*)d_in[2];   // [512][256]
  const float* bemb = (const float*)d_in[3];
  const float* wc = (const float*)d_in[4];     // [8][256][256]
  (void)in_sizes; (void)n_in; (void)out_size; (void)ws_size;

  char* ws = (char*)d_ws;
  size_t o = 0;
  auto alloc = [&](size_t bytes) -> char* {
    char* p = ws + o;
    o = (o + bytes + 511) & ~(size_t)511;
    return p;
  };
  // total workspace ~118.2 MB
  _Float16* hh      = (_Float16*)alloc((size_t)NNODES * HC * 2);  // 51.2 MB
  _Float16* h0h     = (_Float16*)alloc((size_t)NNODES * HC * 2);  // 51.2 MB
  EdgeP*    ep      = (EdgeP*)alloc((size_t)NEDGES * 8);          // 12.8 MB
  _Float16* wembT   = (_Float16*)alloc((size_t)INC * HC * 2);     // 0.26 MB
  _Float16* wcT     = (_Float16*)alloc((size_t)NLAYERS * HC * HC * 2);  // 1.05 MB
  int*      counts  = (int*)alloc((size_t)NNODES * 4);
  int*      cursor  = (int*)alloc((size_t)NNODES * 4);
  int*      rowptr  = (int*)alloc((size_t)(NNODES + 1) * 4);
  float*    dinv    = (float*)alloc((size_t)NNODES * 4);
  int*      partials= (int*)alloc(2048);
  int*      mode    = (int*)alloc(256);
  float*    mf      = (float*)d_out;           // f32 message/identity buffer lives in d_out

  const int NB = (NNODES + 255) / 256;       // 391
  const int GEMM_GRID = (NNODES + 63) / 64;  // 1563

  k_detect<<<1, 64, 0, stream>>>((const unsigned int*)ei, mode);
  k_zero2<<<NB, 256, 0, stream>>>(counts, cursor, NNODES);
  k_tr_wemb<<<(INC * HC) / 256, 256, 0, stream>>>(wemb, wembT);
  k_tr_wc<<<(NLAYERS * HC * HC) / 256, 256, 0, stream>>>(wc, wcT);
  k_count<<<(NEDGES + 255) / 256, 256, 0, stream>>>(ei, mode, counts);
  k_dinv<<<NB, 256, 0, stream>>>(counts, dinv);
  k_scan1<<<NB, 256, 0, stream>>>(counts, rowptr, partials);
  k_scan2<<<1, 512, 0, stream>>>(partials, rowptr, NB);
  k_scan3<<<NB, 256, 0, stream>>>(rowptr, partials);
  k_fill<<<(NEDGES + 255) / 256, 256, 0, stream>>>(ei, mode, rowptr, cursor, dinv, ep);

  // h0 = relu(x @ Wemb + b); stored f16 into hh and h0h
  k_dense<<<GEMM_GRID, 256, 0, stream>>>(x, INC, INC, wembT, bemb,
                                         (const float*)nullptr, 0.0f, 1.0f, 1,
                                         hh, h0h, (float*)nullptr);

  for (int l = 0; l < NLAYERS; ++l) {
    float beta = (float)log(0.5 / (double)(l + 1) + 1.0);
    float ob = 1.0f - beta;
    k_spmm<<<NNODES / 4, 256, 0, stream>>>(hh, h0h, rowptr, ep, dinv, mf);
    bool last = (l == NLAYERS - 1);
    // out = ob*mf + beta*(mf @ W); relu except last; last writes f32 in-place into d_out
    k_dense<<<GEMM_GRID, 256, 0, stream>>>(mf, HC, HC, wcT + (size_t)l * HC * HC,
                                           (const float*)nullptr, mf, ob, beta, last ? 0 : 1,
                                           last ? (_Float16*)nullptr : hh,
                                           (_Float16*)nullptr,
                                           last ? (float*)d_out : (float*)nullptr);
  }
}

// Round 5
// 2338.311 us; speedup vs baseline: 1.2922x; 1.1318x over previous
//
#include <hip/hip_runtime.h>
#include <cmath>

#define NNODES 100000
#define NEDGES 1600000
#define INC 512
#define HC 256
#define NLAYERS 8

typedef _Float16 half8 __attribute__((ext_vector_type(8)));
typedef _Float16 half4v __attribute__((ext_vector_type(4)));
typedef float floatx4 __attribute__((ext_vector_type(4)));

struct __attribute__((aligned(8))) EdgeP { int s; float w; };

// ---- edge dtype detection: int64 little-endian with values < 2^31 => odd 32-bit words all zero.
__global__ void k_detect(const unsigned int* __restrict__ eb, int* __restrict__ mode) {
  int lane = threadIdx.x;  // 64 threads
  unsigned v = eb[2 * lane + 1];
  unsigned long long nz = __ballot(v != 0u);
  if (lane == 0) *mode = (nz == 0ull) ? 1 : 0;
}

__device__ __forceinline__ int edge_at(const void* eb, int m, int i) {
  return m ? (int)((const long long*)eb)[i] : ((const int*)eb)[i];
}

// ---------------- CSR build (unchanged from green R3/R4) ----------------

__global__ __launch_bounds__(256) void k_zero2(int* __restrict__ a, int* __restrict__ b, int n) {
  int i = blockIdx.x * 256 + threadIdx.x;
  if (i < n) { a[i] = 0; b[i] = 0; }
}

__global__ __launch_bounds__(256) void k_count(const void* __restrict__ eb, const int* __restrict__ mode,
                                               int* __restrict__ counts) {
  int e = blockIdx.x * 256 + threadIdx.x;
  if (e >= NEDGES) return;
  int m = *mode;
  atomicAdd(&counts[edge_at(eb, m, NEDGES + e)], 1);
}

__global__ __launch_bounds__(256) void k_dinv(const int* __restrict__ counts, float* __restrict__ dinv) {
  int i = blockIdx.x * 256 + threadIdx.x;
  if (i < NNODES) dinv[i] = 1.0f / sqrtf((float)counts[i] + 1.0f);  // +1 self loop
}

__global__ __launch_bounds__(256) void k_scan1(const int* __restrict__ counts, int* __restrict__ rowptr,
                                               int* __restrict__ partials) {
  __shared__ int sm[256];
  int i = blockIdx.x * 256 + threadIdx.x;
  int v = (i < NNODES) ? counts[i] : 0;
  sm[threadIdx.x] = v;
  __syncthreads();
  for (int off = 1; off < 256; off <<= 1) {
    int u = (threadIdx.x >= off) ? sm[threadIdx.x - off] : 0;
    __syncthreads();
    sm[threadIdx.x] += u;
    __syncthreads();
  }
  if (i < NNODES) rowptr[i] = sm[threadIdx.x] - v;
  if (threadIdx.x == 255) partials[blockIdx.x] = sm[255];
}

__global__ __launch_bounds__(512) void k_scan2(int* __restrict__ partials, int* __restrict__ rowptr, int nb) {
  __shared__ int sm[512];
  int t = threadIdx.x;
  int v = (t < nb) ? partials[t] : 0;
  sm[t] = v;
  __syncthreads();
  for (int off = 1; off < 512; off <<= 1) {
    int u = (t >= off) ? sm[t - off] : 0;
    __syncthreads();
    sm[t] += u;
    __syncthreads();
  }
  if (t < nb) partials[t] = sm[t] - v;
  if (t == 0) rowptr[NNODES] = NEDGES;
}

__global__ __launch_bounds__(256) void k_scan3(int* __restrict__ rowptr, const int* __restrict__ partials) {
  int i = blockIdx.x * 256 + threadIdx.x;
  if (i < NNODES) rowptr[i] += partials[blockIdx.x];
}

__global__ __launch_bounds__(256) void k_fill(const void* __restrict__ eb, const int* __restrict__ mode,
                                              const int* __restrict__ rowptr,
                                              int* __restrict__ cursor, const float* __restrict__ dinv,
                                              EdgeP* __restrict__ ep) {
  int e = blockIdx.x * 256 + threadIdx.x;
  if (e >= NEDGES) return;
  int m = *mode;
  int r = edge_at(eb, m, e), c = edge_at(eb, m, NEDGES + e);
  int p = rowptr[c] + atomicAdd(&cursor[c], 1);
  EdgeP pr; pr.s = r; pr.w = dinv[r] * dinv[c];
  ep[p] = pr;
}

// ---------------- weight transposes to f16 ----------------
__global__ __launch_bounds__(256) void k_tr_wemb(const float* __restrict__ W, _Float16* __restrict__ WT) {
  int idx = blockIdx.x * 256 + threadIdx.x;        // 131072 = c*512 + k
  int k = idx & 511, c = idx >> 9;
  WT[idx] = (_Float16)W[k * 256 + c];
}
__global__ __launch_bounds__(256) void k_tr_wc(const float* __restrict__ W, _Float16* __restrict__ WT) {
  int idx = blockIdx.x * 256 + threadIdx.x;        // 524288 = l*65536 + n*256 + k
  int k = idx & 255, n = (idx >> 8) & 255, l = idx >> 16;
  WT[idx] = (_Float16)W[(l * 256 + k) * 256 + n];
}

// ---------------- MFMA dense: out = act( ob*mfid + beta*(A @ WT^T) + bias ) ----------------
// Block: 64 rows x 256 cols, 4 waves; wave w owns cols w*64..w*64+63.
// Compile-time K -> full unroll -> deep load pipelining.
// F16OUT: results staged in padded LDS, stored as coalesced half8 (fixes 2x write amp).
// !F16OUT (last layer, f32): direct stores (full 64B lines); in-place safe:
// barrier separates all A reads from stores; each (row,col) owned by one thread.

template <int K, bool BIAS, bool ID, bool RELU, bool F16OUT>
__global__ __launch_bounds__(256) void k_dense(const float* A, const _Float16* __restrict__ WT,
                                               const float* __restrict__ bias,
                                               const float* mfid,
                                               float ob, float beta,
                                               _Float16* __restrict__ outh, _Float16* __restrict__ outh2,
                                               float* outf) {
  int t = threadIdx.x;
  int wave = t >> 6, lane = t & 63;
  int r = lane & 15, g = lane >> 4;
  int row0 = blockIdx.x * 64;
  int c0 = wave * 64;
  int ar[4];
#pragma unroll
  for (int rt = 0; rt < 4; ++rt) {
    int rr = row0 + rt * 16 + r;
    ar[rt] = (rr < NNODES) ? rr : (NNODES - 1);
  }
  floatx4 acc[4][4] = {};
#pragma unroll
  for (int ks = 0; ks < K; ks += 32) {
    half8 a[4], b[4];
#pragma unroll
    for (int rt = 0; rt < 4; ++rt) {
      const float* ap = A + (size_t)ar[rt] * K + ks + g * 8;
      float4 p0 = *(const float4*)ap;
      float4 p1 = *(const float4*)(ap + 4);
      a[rt] = half8{ (_Float16)p0.x, (_Float16)p0.y, (_Float16)p0.z, (_Float16)p0.w,
                     (_Float16)p1.x, (_Float16)p1.y, (_Float16)p1.z, (_Float16)p1.w };
    }
#pragma unroll
    for (int ct = 0; ct < 4; ++ct)
      b[ct] = *(const half8*)(WT + (size_t)(c0 + ct * 16 + r) * K + ks + g * 8);
#pragma unroll
    for (int rt = 0; rt < 4; ++rt)
#pragma unroll
      for (int ct = 0; ct < 4; ++ct)
        acc[rt][ct] = __builtin_amdgcn_mfma_f32_16x16x32_f16(a[rt], b[ct], acc[rt][ct], 0, 0, 0);
  }

  if constexpr (!F16OUT) {
    __syncthreads();   // in-place safety: all A reads complete before stores
#pragma unroll
    for (int rt = 0; rt < 4; ++rt) {
#pragma unroll
      for (int q = 0; q < 4; ++q) {
        int row = row0 + rt * 16 + g * 4 + q;
        if (row >= NNODES) continue;
#pragma unroll
        for (int ct = 0; ct < 4; ++ct) {
          int col = c0 + ct * 16 + r;
          size_t off = (size_t)row * HC + col;
          float v = acc[rt][ct][q];
          if constexpr (ID) v = ob * mfid[off] + beta * v;
          if constexpr (BIAS) v += bias[col];
          if constexpr (RELU) v = fmaxf(v, 0.0f);
          outf[off] = v;
        }
      }
    }
  } else {
    __shared__ _Float16 Cl[64][264];   // +8 f16 pad: 16B-aligned rows, spread banks
#pragma unroll
    for (int rt = 0; rt < 4; ++rt) {
#pragma unroll
      for (int q = 0; q < 4; ++q) {
        int lrow = rt * 16 + g * 4 + q;
        int row = row0 + lrow;
        int crow = (row < NNODES) ? row : (NNODES - 1);   // clamp for mfid read
#pragma unroll
        for (int ct = 0; ct < 4; ++ct) {
          int col = c0 + ct * 16 + r;
          float v = acc[rt][ct][q];
          if constexpr (ID) v = ob * mfid[(size_t)crow * HC + col] + beta * v;
          if constexpr (BIAS) v += bias[col];
          if constexpr (RELU) v = fmaxf(v, 0.0f);
          Cl[lrow][col] = (_Float16)v;
        }
      }
    }
    __syncthreads();
    int lrow = t >> 2, cc = (t & 3) * 64;
    int grow = row0 + lrow;
    if (grow < NNODES) {
      size_t base = (size_t)grow * HC + cc;
#pragma unroll
      for (int i = 0; i < 8; ++i) {
        half8 v = *(const half8*)&Cl[lrow][cc + i * 8];
        *(half8*)(outh + base + i * 8) = v;
        if (outh2) *(half8*)(outh2 + base + i * 8) = v;
      }
    }
  }
}

// ---------------- SpMM + residual: mf = 0.9*(D^-1/2 A_hat D^-1/2 h) + 0.1*h0 ----------------

__global__ __launch_bounds__(256) void k_spmm(const _Float16* __restrict__ h, const _Float16* __restrict__ h0,
                                              const int* __restrict__ rowptr, const EdgeP* __restrict__ ep,
                                              const float* __restrict__ dinv, float* __restrict__ mf) {
  int wave = threadIdx.x >> 6, lane = threadIdx.x & 63;
  int node = blockIdx.x * 4 + wave;
  if (node >= NNODES) return;
  int c = lane * 4;
  size_t base = (size_t)node * HC + c;
  float di = dinv[node];
  float ws = di * di;
  half4v hv = *(const half4v*)(h + base);
  float a0 = ws * (float)hv[0], a1 = ws * (float)hv[1], a2 = ws * (float)hv[2], a3 = ws * (float)hv[3];
  int t = rowptr[node], en = rowptr[node + 1];
  for (; t + 3 < en; t += 4) {
    EdgeP p0 = ep[t], p1 = ep[t + 1], p2 = ep[t + 2], p3 = ep[t + 3];
    half4v x0 = *(const half4v*)(h + (size_t)p0.s * HC + c);
    half4v x1 = *(const half4v*)(h + (size_t)p1.s * HC + c);
    half4v x2 = *(const half4v*)(h + (size_t)p2.s * HC + c);
    half4v x3 = *(const half4v*)(h + (size_t)p3.s * HC + c);
    a0 += p0.w * (float)x0[0] + p1.w * (float)x1[0] + p2.w * (float)x2[0] + p3.w * (float)x3[0];
    a1 += p0.w * (float)x0[1] + p1.w * (float)x1[1] + p2.w * (float)x2[1] + p3.w * (float)x3[1];
    a2 += p0.w * (float)x0[2] + p1.w * (float)x1[2] + p2.w * (float)x2[2] + p3.w * (float)x3[2];
    a3 += p0.w * (float)x0[3] + p1.w * (float)x1[3] + p2.w * (float)x2[3] + p3.w * (float)x3[3];
  }
  for (; t < en; ++t) {
    EdgeP p0 = ep[t];
    half4v x0 = *(const half4v*)(h + (size_t)p0.s * HC + c);
    a0 += p0.w * (float)x0[0];
    a1 += p0.w * (float)x0[1];
    a2 += p0.w * (float)x0[2];
    a3 += p0.w * (float)x0[3];
  }
  half4v h0v = *(const half4v*)(h0 + base);
  float4 m = make_float4(0.9f * a0 + 0.1f * (float)h0v[0],
                         0.9f * a1 + 0.1f * (float)h0v[1],
                         0.9f * a2 + 0.1f * (float)h0v[2],
                         0.9f * a3 + 0.1f * (float)h0v[3]);
  *(float4*)(mf + base) = m;
}

// ---------------- host ----------------

extern "C" void kernel_launch(void* const* d_in, const int* in_sizes, int n_in,
                              void* d_out, int out_size, void* d_ws, size_t ws_size,
                              hipStream_t stream) {
  const float* x = (const float*)d_in[0];
  const void* ei = d_in[1];                    // int32 or int64 — detected on device
  const float* wemb = (const float*)d_in[2];   // [512][256]
  const float* bemb = (const float*)d_in[3];
  const float* wc = (const float*)d_in[4];     // [8][256][256]
  (void)in_sizes; (void)n_in; (void)out_size; (void)ws_size;

  char* ws = (char*)d_ws;
  size_t o = 0;
  auto alloc = [&](size_t bytes) -> char* {
    char* p = ws + o;
    o = (o + bytes + 511) & ~(size_t)511;
    return p;
  };
  // total workspace ~118.2 MB
  _Float16* hh      = (_Float16*)alloc((size_t)NNODES * HC * 2);  // 51.2 MB
  _Float16* h0h     = (_Float16*)alloc((size_t)NNODES * HC * 2);  // 51.2 MB
  EdgeP*    ep      = (EdgeP*)alloc((size_t)NEDGES * 8);          // 12.8 MB
  _Float16* wembT   = (_Float16*)alloc((size_t)INC * HC * 2);     // 0.26 MB
  _Float16* wcT     = (_Float16*)alloc((size_t)NLAYERS * HC * HC * 2);  // 1.05 MB
  int*      counts  = (int*)alloc((size_t)NNODES * 4);
  int*      cursor  = (int*)alloc((size_t)NNODES * 4);
  int*      rowptr  = (int*)alloc((size_t)(NNODES + 1) * 4);
  float*    dinv    = (float*)alloc((size_t)NNODES * 4);
  int*      partials= (int*)alloc(2048);
  int*      mode    = (int*)alloc(256);
  float*    mf      = (float*)d_out;           // f32 message/identity buffer lives in d_out

  const int NB = (NNODES + 255) / 256;       // 391
  const int GEMM_GRID = (NNODES + 63) / 64;  // 1563

  k_detect<<<1, 64, 0, stream>>>((const unsigned int*)ei, mode);
  k_zero2<<<NB, 256, 0, stream>>>(counts, cursor, NNODES);
  k_tr_wemb<<<(INC * HC) / 256, 256, 0, stream>>>(wemb, wembT);
  k_tr_wc<<<(NLAYERS * HC * HC) / 256, 256, 0, stream>>>(wc, wcT);
  k_count<<<(NEDGES + 255) / 256, 256, 0, stream>>>(ei, mode, counts);
  k_dinv<<<NB, 256, 0, stream>>>(counts, dinv);
  k_scan1<<<NB, 256, 0, stream>>>(counts, rowptr, partials);
  k_scan2<<<1, 512, 0, stream>>>(partials, rowptr, NB);
  k_scan3<<<NB, 256, 0, stream>>>(rowptr, partials);
  k_fill<<<(NEDGES + 255) / 256, 256, 0, stream>>>(ei, mode, rowptr, cursor, dinv, ep);

  // h0 = relu(x @ Wemb + b); stored f16 into hh and h0h
  k_dense<INC, true, false, true, true><<<GEMM_GRID, 256, 0, stream>>>(
      x, wembT, bemb, (const float*)nullptr, 0.0f, 1.0f, hh, h0h, (float*)nullptr);

  for (int l = 0; l < NLAYERS; ++l) {
    float beta = (float)log(0.5 / (double)(l + 1) + 1.0);
    float ob = 1.0f - beta;
    k_spmm<<<NNODES / 4, 256, 0, stream>>>(hh, h0h, rowptr, ep, dinv, mf);
    bool last = (l == NLAYERS - 1);
    if (!last) {
      k_dense<HC, false, true, true, true><<<GEMM_GRID, 256, 0, stream>>>(
          mf, wcT + (size_t)l * HC * HC, (const float*)nullptr, mf, ob, beta,
          hh, (_Float16*)nullptr, (float*)nullptr);
    } else {
      k_dense<HC, false, true, false, false><<<GEMM_GRID, 256, 0, stream>>>(
          mf, wcT + (size_t)l * HC * HC, (const float*)nullptr, mf, ob, beta,
          (_Float16*)nullptr, (_Float16*)nullptr, (float*)d_out);
    }
  }
}

// Round 6
// 2062.804 us; speedup vs baseline: 1.4648x; 1.1336x over previous
//
#include <hip/hip_runtime.h>
#include <cmath>

#define NNODES 100000
#define NEDGES 1600000
#define INC 512
#define HC 256
#define NLAYERS 8

typedef _Float16 half8 __attribute__((ext_vector_type(8)));
typedef _Float16 half4v __attribute__((ext_vector_type(4)));
typedef float floatx4 __attribute__((ext_vector_type(4)));

struct __attribute__((aligned(8))) EdgeP { int s; float w; };

// ---- edge dtype detection: int64 little-endian with values < 2^31 => odd 32-bit words all zero.
__global__ void k_detect(const unsigned int* __restrict__ eb, int* __restrict__ mode) {
  int lane = threadIdx.x;  // 64 threads
  unsigned v = eb[2 * lane + 1];
  unsigned long long nz = __ballot(v != 0u);
  if (lane == 0) *mode = (nz == 0ull) ? 1 : 0;
}

__device__ __forceinline__ int edge_at(const void* eb, int m, int i) {
  return m ? (int)((const long long*)eb)[i] : ((const int*)eb)[i];
}

// ---------------- CSR build (unchanged, green since R3) ----------------

__global__ __launch_bounds__(256) void k_zero2(int* __restrict__ a, int* __restrict__ b, int n) {
  int i = blockIdx.x * 256 + threadIdx.x;
  if (i < n) { a[i] = 0; b[i] = 0; }
}

__global__ __launch_bounds__(256) void k_count(const void* __restrict__ eb, const int* __restrict__ mode,
                                               int* __restrict__ counts) {
  int e = blockIdx.x * 256 + threadIdx.x;
  if (e >= NEDGES) return;
  int m = *mode;
  atomicAdd(&counts[edge_at(eb, m, NEDGES + e)], 1);
}

__global__ __launch_bounds__(256) void k_dinv(const int* __restrict__ counts, float* __restrict__ dinv) {
  int i = blockIdx.x * 256 + threadIdx.x;
  if (i < NNODES) dinv[i] = 1.0f / sqrtf((float)counts[i] + 1.0f);  // +1 self loop
}

__global__ __launch_bounds__(256) void k_scan1(const int* __restrict__ counts, int* __restrict__ rowptr,
                                               int* __restrict__ partials) {
  __shared__ int sm[256];
  int i = blockIdx.x * 256 + threadIdx.x;
  int v = (i < NNODES) ? counts[i] : 0;
  sm[threadIdx.x] = v;
  __syncthreads();
  for (int off = 1; off < 256; off <<= 1) {
    int u = (threadIdx.x >= off) ? sm[threadIdx.x - off] : 0;
    __syncthreads();
    sm[threadIdx.x] += u;
    __syncthreads();
  }
  if (i < NNODES) rowptr[i] = sm[threadIdx.x] - v;
  if (threadIdx.x == 255) partials[blockIdx.x] = sm[255];
}

__global__ __launch_bounds__(512) void k_scan2(int* __restrict__ partials, int* __restrict__ rowptr, int nb) {
  __shared__ int sm[512];
  int t = threadIdx.x;
  int v = (t < nb) ? partials[t] : 0;
  sm[t] = v;
  __syncthreads();
  for (int off = 1; off < 512; off <<= 1) {
    int u = (t >= off) ? sm[t - off] : 0;
    __syncthreads();
    sm[t] += u;
    __syncthreads();
  }
  if (t < nb) partials[t] = sm[t] - v;
  if (t == 0) rowptr[NNODES] = NEDGES;
}

__global__ __launch_bounds__(256) void k_scan3(int* __restrict__ rowptr, const int* __restrict__ partials) {
  int i = blockIdx.x * 256 + threadIdx.x;
  if (i < NNODES) rowptr[i] += partials[blockIdx.x];
}

__global__ __launch_bounds__(256) void k_fill(const void* __restrict__ eb, const int* __restrict__ mode,
                                              const int* __restrict__ rowptr,
                                              int* __restrict__ cursor, const float* __restrict__ dinv,
                                              EdgeP* __restrict__ ep) {
  int e = blockIdx.x * 256 + threadIdx.x;
  if (e >= NEDGES) return;
  int m = *mode;
  int r = edge_at(eb, m, e), c = edge_at(eb, m, NEDGES + e);
  int p = rowptr[c] + atomicAdd(&cursor[c], 1);
  EdgeP pr; pr.s = r; pr.w = dinv[r] * dinv[c];
  ep[p] = pr;
}

// ---------------- weight transposes to f16 ----------------
__global__ __launch_bounds__(256) void k_tr_wemb(const float* __restrict__ W, _Float16* __restrict__ WT) {
  int idx = blockIdx.x * 256 + threadIdx.x;        // 131072 = c*512 + k
  int k = idx & 511, c = idx >> 9;
  WT[idx] = (_Float16)W[k * 256 + c];
}
__global__ __launch_bounds__(256) void k_tr_wc(const float* __restrict__ W, _Float16* __restrict__ WT) {
  int idx = blockIdx.x * 256 + threadIdx.x;        // 524288 = l*65536 + n*256 + k
  int k = idx & 255, n = (idx >> 8) & 255, l = idx >> 16;
  WT[idx] = (_Float16)W[(l * 256 + k) * 256 + n];
}

// ---------------- MFMA dense: out = act( ob*mfid + beta*(A @ WT^T) + bias ) ----------------
// Block: 64 rows x 256 cols, 4 waves; wave w owns cols w*64..w*64+63.
// Explicit 2-deep register double-buffer: loads for K-step k+1 issued before MFMAs
// of step k -> 2 iterations of loads in flight (R5 counters showed exactly 1).
// AF16: A rows are f16 (mid layers, direct MFMA operand). Else f32 + in-reg cvt.
// F16OUT: stage in padded LDS, store coalesced half8.
// !F16OUT (last layer, f32): direct stores; in-place safe (barrier drains all
// A reads before stores; each (row,col) owned by exactly one thread).

template <int K, bool AF16, bool BIAS, bool ID, bool RELU, bool F16OUT>
__global__ __launch_bounds__(256) void k_dense(const void* A, const _Float16* __restrict__ WT,
                                               const float* __restrict__ bias,
                                               const void* mfid,
                                               float ob, float beta,
                                               _Float16* __restrict__ outh, _Float16* __restrict__ outh2,
                                               float* outf) {
  int t = threadIdx.x;
  int wave = t >> 6, lane = t & 63;
  int r = lane & 15, g = lane >> 4;
  int row0 = blockIdx.x * 64;
  int c0 = wave * 64;
  int ar[4];
#pragma unroll
  for (int rt = 0; rt < 4; ++rt) {
    int rr = row0 + rt * 16 + r;
    ar[rt] = (rr < NNODES) ? rr : (NNODES - 1);
  }

  auto loadA = [&](half8 (&a)[4], int ks) {
#pragma unroll
    for (int rt = 0; rt < 4; ++rt) {
      if constexpr (AF16) {
        a[rt] = *(const half8*)((const _Float16*)A + (size_t)ar[rt] * K + ks + g * 8);
      } else {
        const float* ap = (const float*)A + (size_t)ar[rt] * K + ks + g * 8;
        float4 p0 = *(const float4*)ap;
        float4 p1 = *(const float4*)(ap + 4);
        a[rt] = half8{ (_Float16)p0.x, (_Float16)p0.y, (_Float16)p0.z, (_Float16)p0.w,
                       (_Float16)p1.x, (_Float16)p1.y, (_Float16)p1.z, (_Float16)p1.w };
      }
    }
  };
  auto loadB = [&](half8 (&b)[4], int ks) {
#pragma unroll
    for (int ct = 0; ct < 4; ++ct)
      b[ct] = *(const half8*)(WT + (size_t)(c0 + ct * 16 + r) * K + ks + g * 8);
  };

  floatx4 acc[4][4] = {};
  half8 aP[4], bP[4], aQ[4], bQ[4];
  loadA(aP, 0); loadB(bP, 0);
#pragma unroll
  for (int ks = 0; ks < K; ks += 64) {
    loadA(aQ, ks + 32); loadB(bQ, ks + 32);
#pragma unroll
    for (int rt = 0; rt < 4; ++rt)
#pragma unroll
      for (int ct = 0; ct < 4; ++ct)
        acc[rt][ct] = __builtin_amdgcn_mfma_f32_16x16x32_f16(aP[rt], bP[ct], acc[rt][ct], 0, 0, 0);
    if (ks + 64 < K) { loadA(aP, ks + 64); loadB(bP, ks + 64); }
#pragma unroll
    for (int rt = 0; rt < 4; ++rt)
#pragma unroll
      for (int ct = 0; ct < 4; ++ct)
        acc[rt][ct] = __builtin_amdgcn_mfma_f32_16x16x32_f16(aQ[rt], bQ[ct], acc[rt][ct], 0, 0, 0);
  }

  auto idval = [&](size_t off) -> float {
    if constexpr (AF16) return (float)((const _Float16*)mfid)[off];
    else return ((const float*)mfid)[off];
  };

  if constexpr (!F16OUT) {
    __syncthreads();   // in-place safety: all A reads drained before stores
#pragma unroll
    for (int rt = 0; rt < 4; ++rt) {
#pragma unroll
      for (int q = 0; q < 4; ++q) {
        int row = row0 + rt * 16 + g * 4 + q;
        if (row >= NNODES) continue;
#pragma unroll
        for (int ct = 0; ct < 4; ++ct) {
          int col = c0 + ct * 16 + r;
          size_t off = (size_t)row * HC + col;
          float v = acc[rt][ct][q];
          if constexpr (ID) v = ob * idval(off) + beta * v;
          if constexpr (BIAS) v += bias[col];
          if constexpr (RELU) v = fmaxf(v, 0.0f);
          outf[off] = v;
        }
      }
    }
  } else {
    __shared__ _Float16 Cl[64][264];   // +8 f16 pad
#pragma unroll
    for (int rt = 0; rt < 4; ++rt) {
#pragma unroll
      for (int q = 0; q < 4; ++q) {
        int lrow = rt * 16 + g * 4 + q;
        int row = row0 + lrow;
        int crow = (row < NNODES) ? row : (NNODES - 1);   // clamp for mfid read
#pragma unroll
        for (int ct = 0; ct < 4; ++ct) {
          int col = c0 + ct * 16 + r;
          float v = acc[rt][ct][q];
          if constexpr (ID) v = ob * idval((size_t)crow * HC + col) + beta * v;
          if constexpr (BIAS) v += bias[col];
          if constexpr (RELU) v = fmaxf(v, 0.0f);
          Cl[lrow][col] = (_Float16)v;
        }
      }
    }
    __syncthreads();
    int lrow = t >> 2, cc = (t & 3) * 64;
    int grow = row0 + lrow;
    if (grow < NNODES) {
      size_t base = (size_t)grow * HC + cc;
#pragma unroll
      for (int i = 0; i < 8; ++i) {
        half8 v = *(const half8*)&Cl[lrow][cc + i * 8];
        *(half8*)(outh + base + i * 8) = v;
        if (outh2) *(half8*)(outh2 + base + i * 8) = v;
      }
    }
  }
}

// ---------------- SpMM + residual: m = 0.9*(D^-1/2 A_hat D^-1/2 h) + 0.1*h0 ----------------
// F16OUT: mid layers write f16 message (halves write bytes); last layer writes f32.

template <bool F16OUT>
__global__ __launch_bounds__(256) void k_spmm(const _Float16* __restrict__ h, const _Float16* __restrict__ h0,
                                              const int* __restrict__ rowptr, const EdgeP* __restrict__ ep,
                                              const float* __restrict__ dinv,
                                              float* __restrict__ mf, _Float16* __restrict__ mh) {
  int wave = threadIdx.x >> 6, lane = threadIdx.x & 63;
  int node = blockIdx.x * 4 + wave;
  if (node >= NNODES) return;
  int c = lane * 4;
  size_t base = (size_t)node * HC + c;
  float di = dinv[node];
  float ws = di * di;
  half4v hv = *(const half4v*)(h + base);
  float a0 = ws * (float)hv[0], a1 = ws * (float)hv[1], a2 = ws * (float)hv[2], a3 = ws * (float)hv[3];
  int t = rowptr[node], en = rowptr[node + 1];
  for (; t + 3 < en; t += 4) {
    EdgeP p0 = ep[t], p1 = ep[t + 1], p2 = ep[t + 2], p3 = ep[t + 3];
    half4v x0 = *(const half4v*)(h + (size_t)p0.s * HC + c);
    half4v x1 = *(const half4v*)(h + (size_t)p1.s * HC + c);
    half4v x2 = *(const half4v*)(h + (size_t)p2.s * HC + c);
    half4v x3 = *(const half4v*)(h + (size_t)p3.s * HC + c);
    a0 += p0.w * (float)x0[0] + p1.w * (float)x1[0] + p2.w * (float)x2[0] + p3.w * (float)x3[0];
    a1 += p0.w * (float)x0[1] + p1.w * (float)x1[1] + p2.w * (float)x2[1] + p3.w * (float)x3[1];
    a2 += p0.w * (float)x0[2] + p1.w * (float)x1[2] + p2.w * (float)x2[2] + p3.w * (float)x3[2];
    a3 += p0.w * (float)x0[3] + p1.w * (float)x1[3] + p2.w * (float)x2[3] + p3.w * (float)x3[3];
  }
  for (; t < en; ++t) {
    EdgeP p0 = ep[t];
    half4v x0 = *(const half4v*)(h + (size_t)p0.s * HC + c);
    a0 += p0.w * (float)x0[0];
    a1 += p0.w * (float)x0[1];
    a2 += p0.w * (float)x0[2];
    a3 += p0.w * (float)x0[3];
  }
  half4v h0v = *(const half4v*)(h0 + base);
  float m0 = 0.9f * a0 + 0.1f * (float)h0v[0];
  float m1 = 0.9f * a1 + 0.1f * (float)h0v[1];
  float m2 = 0.9f * a2 + 0.1f * (float)h0v[2];
  float m3 = 0.9f * a3 + 0.1f * (float)h0v[3];
  if constexpr (F16OUT) {
    half4v mo = { (_Float16)m0, (_Float16)m1, (_Float16)m2, (_Float16)m3 };
    *(half4v*)(mh + base) = mo;
  } else {
    *(float4*)(mf + base) = make_float4(m0, m1, m2, m3);
  }
}

// ---------------- host ----------------

extern "C" void kernel_launch(void* const* d_in, const int* in_sizes, int n_in,
                              void* d_out, int out_size, void* d_ws, size_t ws_size,
                              hipStream_t stream) {
  const float* x = (const float*)d_in[0];
  const void* ei = d_in[1];                    // int32 or int64 — detected on device
  const float* wemb = (const float*)d_in[2];   // [512][256]
  const float* bemb = (const float*)d_in[3];
  const float* wc = (const float*)d_in[4];     // [8][256][256]
  (void)in_sizes; (void)n_in; (void)out_size; (void)ws_size;

  char* ws = (char*)d_ws;
  size_t o = 0;
  auto alloc = [&](size_t bytes) -> char* {
    char* p = ws + o;
    o = (o + bytes + 511) & ~(size_t)511;
    return p;
  };
  // total workspace ~118.2 MB
  _Float16* hh      = (_Float16*)alloc((size_t)NNODES * HC * 2);  // 51.2 MB
  _Float16* h0h     = (_Float16*)alloc((size_t)NNODES * HC * 2);  // 51.2 MB
  EdgeP*    ep      = (EdgeP*)alloc((size_t)NEDGES * 8);          // 12.8 MB
  _Float16* wembT   = (_Float16*)alloc((size_t)INC * HC * 2);     // 0.26 MB
  _Float16* wcT     = (_Float16*)alloc((size_t)NLAYERS * HC * HC * 2);  // 1.05 MB
  int*      counts  = (int*)alloc((size_t)NNODES * 4);
  int*      cursor  = (int*)alloc((size_t)NNODES * 4);
  int*      rowptr  = (int*)alloc((size_t)(NNODES + 1) * 4);
  float*    dinv    = (float*)alloc((size_t)NNODES * 4);
  int*      partials= (int*)alloc(2048);
  int*      mode    = (int*)alloc(256);
  // message buffer lives in d_out: f16 for mid layers (first 51.2 MB), f32 full for last
  _Float16* mh      = (_Float16*)d_out;
  float*    mf      = (float*)d_out;

  const int NB = (NNODES + 255) / 256;       // 391
  const int GEMM_GRID = (NNODES + 63) / 64;  // 1563

  k_detect<<<1, 64, 0, stream>>>((const unsigned int*)ei, mode);
  k_zero2<<<NB, 256, 0, stream>>>(counts, cursor, NNODES);
  k_tr_wemb<<<(INC * HC) / 256, 256, 0, stream>>>(wemb, wembT);
  k_tr_wc<<<(NLAYERS * HC * HC) / 256, 256, 0, stream>>>(wc, wcT);
  k_count<<<(NEDGES + 255) / 256, 256, 0, stream>>>(ei, mode, counts);
  k_dinv<<<NB, 256, 0, stream>>>(counts, dinv);
  k_scan1<<<NB, 256, 0, stream>>>(counts, rowptr, partials);
  k_scan2<<<1, 512, 0, stream>>>(partials, rowptr, NB);
  k_scan3<<<NB, 256, 0, stream>>>(rowptr, partials);
  k_fill<<<(NEDGES + 255) / 256, 256, 0, stream>>>(ei, mode, rowptr, cursor, dinv, ep);

  // h0 = relu(x @ Wemb + b); stored f16 into hh and h0h
  k_dense<INC, false, true, false, true, true><<<GEMM_GRID, 256, 0, stream>>>(
      x, wembT, bemb, (const void*)nullptr, 0.0f, 1.0f, hh, h0h, (float*)nullptr);

  for (int l = 0; l < NLAYERS; ++l) {
    float beta = (float)log(0.5 / (double)(l + 1) + 1.0);
    float ob = 1.0f - beta;
    bool last = (l == NLAYERS - 1);
    if (!last) {
      k_spmm<true><<<NNODES / 4, 256, 0, stream>>>(hh, h0h, rowptr, ep, dinv,
                                                   (float*)nullptr, mh);
      // hh = relu(ob*m + beta*(m @ W)), m read f16
      k_dense<HC, true, false, true, true, true><<<GEMM_GRID, 256, 0, stream>>>(
          mh, wcT + (size_t)l * HC * HC, (const float*)nullptr, mh, ob, beta,
          hh, (_Float16*)nullptr, (float*)nullptr);
    } else {
      k_spmm<false><<<NNODES / 4, 256, 0, stream>>>(hh, h0h, rowptr, ep, dinv,
                                                    mf, (_Float16*)nullptr);
      // d_out = ob*mf + beta*(mf @ W), f32 in-place (proven green path)
      k_dense<HC, false, false, true, false, false><<<GEMM_GRID, 256, 0, stream>>>(
          mf, wcT + (size_t)l * HC * HC, (const float*)nullptr, mf, ob, beta,
          (_Float16*)nullptr, (_Float16*)nullptr, (float*)d_out);
    }
  }
}